// Round 9
// baseline (37.306 us; speedup 1.0000x reference)
//
#include <hip/hip_runtime.h>
#include <hip/hip_bf16.h>
#include <math.h>

#define HMAP 800
#define WMAP 800
#define OHW  120
#define NCELL (OHW * OHW)
#define NCH  8
#define NPTS 100000
#define SDIM 32
#define CAP  32
#define NBIN1 121                 // bins per dim: iy0 in [-1,119] -> +1
#define NBINS (NBIN1 * NBIN1)     // 14641

__device__ __forceinline__ float rscale() { return 800.0f / 120.0f; }

__device__ __forceinline__ float clipval(float v) {
    if (isnan(v)) v = 0.f;
    else if (isinf(v)) v = (v > 0.f) ? 0.f : -3.4028234663852886e38f;
    if (v > 255.f) v = 255.f;
    return v;
}

// normalization sum for output index i (same for both dims, both 800->120)
__device__ __forceinline__ float norm_sum(int i) {
    const float r = rscale();
    float c = ((float)i + 0.5f) * r - 0.5f;
    int j0 = (int)ceilf(c - r);
    float s = 0.f;
#pragma unroll
    for (int k = 0; k < 14; ++k) {
        int j = j0 + k;
        if (j < 0 || j >= HMAP) continue;
        s += fmaxf(0.f, 1.f - fabsf(c - (float)j) / r);
    }
    return s;
}

// ---------------- workspace layout (int units) ----------------
#define WS_COUNTS   0
#define WS_SPILLCUR 14641
#define WS_INVS     14656
#define WS_ENTRIES  14784
#define WS_SPILL    (WS_ENTRIES + NBINS * CAP * 2)
#define WS_T        (WS_SPILL + NPTS * 2)
#define WS_P        (WS_T + NCH * WMAP * OHW)
#define WS_END      (WS_P + 4 * NCELL * SDIM)
#define WS_REQ_BYTES ((size_t)WS_END * 4)

#define ZERO_BLOCKS 58                                // 58*256 >= 14656
#define FILL_BLOCKS ((NPTS + 255) / 256)              // 391
#define RY_BLOCKS   (NCH * WMAP / 2)                  // 3200 (2 rows per block)
#define GB_BLOCKS   ((NBINS + 3) / 4)                 // 3661 (4 bins per block)
#define RX_BLOCKS   (NCH * OHW / 2)                   // 480
#define CB_BLOCKS   (NCELL / 16)                      // 900 (16 cells per block)

// ===== K0: zero counts+cursor, compute invS table =====
__global__ void k_zero(int* __restrict__ counts, float* __restrict__ invS) {
    int gid = blockIdx.x * 256 + threadIdx.x;
    if (gid < 14656) counts[gid] = 0;
    if (gid < OHW) invS[gid] = 1.0f / norm_sum(gid);
}

// ===== K1: point binning (blocks [0,391)) + spatial pass Y =====
__global__ void k_phase1(const float* __restrict__ spatial, const int* __restrict__ loc,
                         float* __restrict__ T, int* __restrict__ counts,
                         int2* __restrict__ entries, int2* __restrict__ spill,
                         int* __restrict__ spill_cur) {
    __shared__ float row[2][HMAP];
    if (blockIdx.x < FILL_BLOCKS) {
        int n = blockIdx.x * 256 + threadIdx.x;
        if (n >= NPTS) return;
        int2 xy = ((const int2*)loc)[n];
        int x = min(max(xy.x, 0), WMAP - 1);
        int y = min(max(xy.y, 0), HMAP - 1);
        const float r = rscale();
        int iy0 = (int)floorf(((float)y + 0.5f) / r - 0.5f);
        int ix0 = (int)floorf(((float)x + 0.5f) / r - 0.5f);
        int bin = (iy0 + 1) * NBIN1 + (ix0 + 1);
        int pos = (y << 10) | x;
        int slot = atomicAdd(&counts[bin], 1);
        if (slot < CAP) {
            entries[(size_t)bin * CAP + slot] = make_int2(n, pos);
        } else {  // rare overflow: append to spill list (scanned by bin-gather)
            int s = atomicAdd(spill_cur, 1);
            if (s < NPTS) spill[s] = make_int2((bin << 17) | n, pos);
        }
        return;
    }
    // ---- resize Y: 2 rows (c,xx) per block; T[c][xx][oy] ----
    int bx = (blockIdx.x - FILL_BLOCKS) * 2 + (threadIdx.x >> 7);
    int hw = threadIdx.x & 127;
    int c = bx / WMAP, xx = bx % WMAP;
    int rsel = threadIdx.x >> 7;
    const float* rp = spatial + (size_t)c * (HMAP * WMAP) + (size_t)xx * WMAP;
    for (int j = hw; j < HMAP; j += 128) row[rsel][j] = clipval(rp[j]);
    __syncthreads();
    int oy = hw;
    if (oy >= OHW) return;
    const float r = rscale();
    const float invR = 1.0f / r;
    float cy = ((float)oy + 0.5f) * r - 0.5f;
    int y0 = (int)ceilf(cy - r);
    float acc = 0.f, ws = 0.f;
#pragma unroll
    for (int k = 0; k < 14; ++k) {
        int j = y0 + k;
        float w = fmaxf(0.f, fmaf(-fabsf(cy - (float)j), invR, 1.f));
        w = (j >= 0 && j < HMAP) ? w : 0.f;           // branchless OOB zero
        int jc = min(max(j, 0), HMAP - 1);
        ws += w;
        acc = fmaf(w, row[rsel][HMAP - 1 - jc], acc);
    }
    T[((size_t)c * WMAP + xx) * OHW + oy] = acc / (255.f * ws);
}

// ===== K2: bin-centric gather -> partials (blocks [0,3661)) + resizeX + MLP =====
__global__ void k_phase2(const float* __restrict__ T, const float* __restrict__ emb,
                         const int* __restrict__ counts, const int2* __restrict__ entries,
                         const int2* __restrict__ spill, const int* __restrict__ spill_cur,
                         const float* __restrict__ invS, float* __restrict__ P,
                         float* __restrict__ out,
                         const float* __restrict__ scalar, const float* __restrict__ w1,
                         const float* __restrict__ b1, const float* __restrict__ w2,
                         const float* __restrict__ b2) {
    __shared__ int2 st[4][CAP];
    __shared__ float sh[32];
    int bid = blockIdx.x;
    if (bid < GB_BLOCKS) {
        int t = threadIdx.x;
        int wv = t >> 6;
        int bin = bid * 4 + wv;
        if (bin >= NBINS) return;
        int lane = t & 63;
        int q = lane >> 4;            // corner 0..3: a=q>>1 (dy), b=q&1 (dx)
        int c2 = lane & 15;           // channel pair
        int by = bin / NBIN1, bx = bin % NBIN1;
        int cell_y = by - 1 + (q >> 1);
        int cell_x = bx - 1 + (q & 1);
        bool valid = (cell_y >= 0 && cell_y < OHW && cell_x >= 0 && cell_x < OHW);
        int cyi = min(max(cell_y, 0), OHW - 1), cxi = min(max(cell_x, 0), OHW - 1);
        const float r = rscale();
        const float invR = 1.0f / r;
        float cy = ((float)cell_y + 0.5f) * r - 0.5f;
        float cx = ((float)cell_x + 0.5f) * r - 0.5f;
        float invS2 = valid ? (invS[cyi] * invS[cxi]) : 0.f;

        int craw = counts[bin];
        int cnt = min(craw, CAP);
        // stage entries: one coalesced 256B read (32 int2) into LDS
        if (lane < CAP) st[wv][lane] = entries[(size_t)bin * CAP + lane];
        // wave-local LDS write->read; compiler inserts lgkmcnt wait

        const float2* embp = (const float2*)emb;
        float ax = 0.f, ay = 0.f;
        for (int i = 0; i < cnt; ++i) {
            int2 e = st[wv][i];
            float py = (float)((e.y >> 10) & 1023);
            float px = (float)(e.y & 1023);
            float wy = fmaxf(0.f, fmaf(-fabsf(cy - py), invR, 1.f));
            float wx = fmaxf(0.f, fmaf(-fabsf(cx - px), invR, 1.f));
            float w = wy * wx * invS2;
            float2 v = embp[(size_t)e.x * (SDIM / 2) + c2];   // one 128B line / entry
            ax = fmaf(w, v.x, ax);
            ay = fmaf(w, v.y, ay);
        }
        if (craw > CAP) {                                  // rare: scan spill list
            int sn = min(spill_cur[0], NPTS);
            for (int s = 0; s < sn; ++s) {
                int2 e = spill[s];
                if ((e.x >> 17) == bin) {
                    int n = e.x & 0x1FFFF;
                    float py = (float)((e.y >> 10) & 1023);
                    float px = (float)(e.y & 1023);
                    float wy = fmaxf(0.f, fmaf(-fabsf(cy - py), invR, 1.f));
                    float wx = fmaxf(0.f, fmaf(-fabsf(cx - px), invR, 1.f));
                    float w = wy * wx * invS2;
                    float2 v = embp[(size_t)n * (SDIM / 2) + c2];
                    ax = fmaf(w, v.x, ax); ay = fmaf(w, v.y, ay);
                }
            }
        }
        if (valid) {   // P[q][cell][ch]: 16 lanes x 8B = 128B coalesced per corner
            float2* pp = (float2*)P;
            pp[((size_t)q * NCELL + cell_y * OHW + cell_x) * (SDIM / 2) + c2] =
                make_float2(ax, ay);
        }
        return;
    }
    if (bid < GB_BLOCKS + RX_BLOCKS) {   // resize X: 2 (c,ox) columns per block
        int col = (bid - GB_BLOCKS) * 2 + (threadIdx.x >> 7);
        int oy = threadIdx.x & 127;
        if (oy >= OHW) return;
        int c = col / OHW, ox = col % OHW;
        const float r = rscale();
        const float invR = 1.0f / r;
        float cx = ((float)ox + 0.5f) * r - 0.5f;
        int x0 = (int)ceilf(cx - r);
        float acc = 0.f;
#pragma unroll
        for (int k = 0; k < 14; ++k) {
            int j = x0 + k;
            float w = fmaxf(0.f, fmaf(-fabsf(cx - (float)j), invR, 1.f));
            w = (j >= 0 && j < WMAP) ? w : 0.f;
            int jc = min(max(j, 0), WMAP - 1);
            acc = fmaf(w, T[((size_t)c * WMAP + jc) * OHW + oy], acc);
        }
        out[((size_t)c * OHW + oy) * OHW + ox] = acc * invS[ox];
        return;
    }
    // ---- fused scalar MLP ----
    int j = threadIdx.x;
    if (j < 32) {
        float a = b1[j];
        for (int i = 0; i < 8; ++i) a = fmaf(scalar[i], w1[i * 32 + j], a);
        sh[j] = fmaxf(a, 0.f);
    }
    __syncthreads();
    if (j < 4) {
        float a = b2[j];
        for (int i = 0; i < 32; ++i) a = fmaf(sh[i], w2[i * 4 + j], a);
        out[(size_t)(NCH + SDIM) * NCELL + j] = fmaxf(a, 0.f);
    }
}

// ===== K3: combine 4 corner partials per cell -> out channels 8..39 =====
__global__ void k_combine(const float* __restrict__ P, float* __restrict__ out) {
    int t = threadIdx.x;
    int cell = blockIdx.x * 16 + (t >> 4);
    int c2 = t & 15;
    const float2* pp = (const float2*)P;
    float ax = 0.f, ay = 0.f;
#pragma unroll
    for (int q = 0; q < 4; ++q) {
        float2 v = pp[((size_t)q * NCELL + cell) * (SDIM / 2) + c2];
        ax += v.x; ay += v.y;
    }
    out[(size_t)(NCH + 2 * c2) * NCELL + cell] = ax;
    out[(size_t)(NCH + 2 * c2 + 1) * NCELL + cell] = ay;
}

// ================= fallback path (ws too small): round-1 style ==============
__global__ void k_norm_fb(float* __restrict__ S) {
    int i = blockIdx.x * blockDim.x + threadIdx.x;
    if (i < OHW) S[i] = norm_sum(i);
}

__global__ void k_spatial_fb(const float* __restrict__ spatial, const float* __restrict__ S,
                             float* __restrict__ out) {
    int t = blockIdx.x * blockDim.x + threadIdx.x;
    if (t >= NCH * NCELL) return;
    int c = t / NCELL, rem = t % NCELL;
    int oy = rem / OHW, ox = rem % OHW;
    const float r = rscale();
    float cy = ((float)oy + 0.5f) * r - 0.5f;
    float cx = ((float)ox + 0.5f) * r - 0.5f;
    int y0 = (int)ceilf(cy - r);
    int x0 = (int)ceilf(cx - r);
    const float* sp = spatial + (size_t)c * (HMAP * WMAP);
    float acc = 0.f;
    for (int kx = 0; kx < 14; ++kx) {
        int col = x0 + kx;
        if (col < 0 || col >= WMAP) continue;
        float wxx = fmaxf(0.f, 1.f - fabsf(cx - (float)col) / r);
        if (wxx == 0.f) continue;
        const float* colp = sp + (size_t)col * WMAP;
        float accy = 0.f;
        for (int ky = 0; ky < 14; ++ky) {
            int j = y0 + ky;
            if (j < 0 || j >= HMAP) continue;
            float wyy = fmaxf(0.f, 1.f - fabsf(cy - (float)j) / r);
            accy = fmaf(wyy, clipval(colp[HMAP - 1 - j]), accy);
        }
        acc = fmaf(wxx, accy, acc);
    }
    out[t] = acc * (1.0f / 255.0f) / (S[oy] * S[ox]);
}

__global__ void k_scatter_fb(const float* __restrict__ emb, const int* __restrict__ loc,
                             const float* __restrict__ S, float* __restrict__ out) {
    int t = blockIdx.x * blockDim.x + threadIdx.x;
    if (t >= NPTS * SDIM) return;
    int n = t >> 5, c = t & 31;
    int x = min(max(loc[2 * n + 0], 0), WMAP - 1);
    int y = min(max(loc[2 * n + 1], 0), HMAP - 1);
    float e = emb[t];
    const float r = rscale();
    int iy0 = (int)floorf(((float)y + 0.5f) / r - 0.5f);
    int ix0 = (int)floorf(((float)x + 0.5f) / r - 0.5f);
    float* base = out + (size_t)(NCH + c) * NCELL;
#pragma unroll
    for (int a = 0; a < 2; ++a) {
        int iy = iy0 + a;
        if (iy < 0 || iy >= OHW) continue;
        float cyv = ((float)iy + 0.5f) * r - 0.5f;
        float wy = fmaxf(0.f, 1.f - fabsf(cyv - (float)y) / r) / S[iy];
#pragma unroll
        for (int b = 0; b < 2; ++b) {
            int ix = ix0 + b;
            if (ix < 0 || ix >= OHW) continue;
            float cxv = ((float)ix + 0.5f) * r - 0.5f;
            float wx = fmaxf(0.f, 1.f - fabsf(cxv - (float)x) / r) / S[ix];
            atomicAdd(base + iy * OHW + ix, e * wy * wx);
        }
    }
}

__global__ void k_mlp_fb(const float* __restrict__ scalar, const float* __restrict__ w1,
                         const float* __restrict__ b1, const float* __restrict__ w2,
                         const float* __restrict__ b2, float* __restrict__ out) {
    __shared__ float h[32];
    int j = threadIdx.x;
    if (j < 32) {
        float a = b1[j];
        for (int i = 0; i < 8; ++i) a = fmaf(scalar[i], w1[i * 32 + j], a);
        h[j] = fmaxf(a, 0.f);
    }
    __syncthreads();
    if (j < 4) {
        float a = b2[j];
        for (int i = 0; i < 32; ++i) a = fmaf(h[i], w2[i * 4 + j], a);
        out[(size_t)(NCH + SDIM) * NCELL + j] = fmaxf(a, 0.f);
    }
}

extern "C" void kernel_launch(void* const* d_in, const int* in_sizes, int n_in,
                              void* d_out, int out_size, void* d_ws, size_t ws_size,
                              hipStream_t stream) {
    const float* spatial = (const float*)d_in[0];
    const float* emb     = (const float*)d_in[1];
    const int*   loc     = (const int*)d_in[2];
    const float* scalar  = (const float*)d_in[3];
    const float* w1      = (const float*)d_in[4];
    const float* b1      = (const float*)d_in[5];
    const float* w2      = (const float*)d_in[6];
    const float* b2      = (const float*)d_in[7];
    float* out = (float*)d_out;

    int*   wsi = (int*)d_ws;
    float* wsf = (float*)d_ws;

    if (ws_size >= WS_REQ_BYTES) {
        int*   counts    = wsi + WS_COUNTS;
        int*   spill_cur = wsi + WS_SPILLCUR;
        float* invS      = wsf + WS_INVS;
        int2*  entries   = (int2*)(wsi + WS_ENTRIES);
        int2*  spill     = (int2*)(wsi + WS_SPILL);
        float* T         = wsf + WS_T;
        float* P         = wsf + WS_P;

        k_zero<<<ZERO_BLOCKS, 256, 0, stream>>>(counts, invS);
        k_phase1<<<FILL_BLOCKS + RY_BLOCKS, 256, 0, stream>>>(spatial, loc, T, counts,
                                                              entries, spill, spill_cur);
        k_phase2<<<GB_BLOCKS + RX_BLOCKS + 1, 256, 0, stream>>>(T, emb, counts, entries,
                                                                spill, spill_cur, invS,
                                                                P, out, scalar, w1, b1,
                                                                w2, b2);
        k_combine<<<CB_BLOCKS, 256, 0, stream>>>(P, out);
    } else {
        float* S = wsf;
        hipMemsetAsync(d_out, 0, (size_t)out_size * sizeof(float), stream);
        k_norm_fb<<<1, 128, 0, stream>>>(S);
        k_spatial_fb<<<(NCH * NCELL + 255) / 256, 256, 0, stream>>>(spatial, S, out);
        k_scatter_fb<<<(NPTS * SDIM + 255) / 256, 256, 0, stream>>>(emb, loc, S, out);
        k_mlp_fb<<<1, 64, 0, stream>>>(scalar, w1, b1, w2, b2, out);
    }
}